// Round 11
// baseline (529.093 us; speedup 1.0000x reference)
//
#include <hip/hip_runtime.h>
#include <hip/hip_bf16.h>
#include <hip/hip_cooperative_groups.h>
#include <stdint.h>

namespace cg = cooperative_groups;

// Problem constants
#define NT 4096      // tokens
#define DM 320       // model dim
#define NH 8         // heads
#define DH 40        // head dim
#define DHP 64       // Q row stride (d 40..63 never written; zero-synth in attn)
#define KS 2         // split-K factor over the key dimension
#define GRID 512     // 2 blocks/CU -- co-residency guaranteed (LDS 17.4KB, VGPR<=128)
#define QSCALE 0.22811013f  // (1/sqrt(40)) * log2(e): folded into Q so p = exp2(qk)
#define PSTR 68      // P-tile LDS row stride (ushorts): b64 8B-aligned, <=2-way banks
#define KFJB 640     // Kf shorts per 16-key block: 512 (k<32) + 128 (k=32..39, quad0)

typedef float f32x4 __attribute__((ext_vector_type(4)));
typedef __bf16 bf16x8 __attribute__((ext_vector_type(8)));

__device__ __forceinline__ unsigned short f2b(float f) {
  unsigned u = __builtin_bit_cast(unsigned, f);
  u += 0x7FFFu + ((u >> 16) & 1u);   // RNE
  return (unsigned short)(u >> 16);
}

__device__ __forceinline__ bf16x8 ld_bf8(const unsigned short* p) {
  uint4 v = *(const uint4*)p;        // 16B load
  return __builtin_bit_cast(bf16x8, v);
}

__device__ __forceinline__ f32x4 mfma16(bf16x8 a, bf16x8 b, f32x4 c) {
  return __builtin_amdgcn_mfma_f32_16x16x32_bf16(a, b, c, 0, 0, 0);
}

__device__ __forceinline__ float fexp2(float x) {
#if __has_builtin(__builtin_amdgcn_exp2f)
  return __builtin_amdgcn_exp2f(x);
#else
  float r; asm("v_exp_f32 %0, %1" : "=v"(r) : "v"(x)); return r;
#endif
}

// one-shot software grid barrier (device-scope atomics; bar zeroed before launch)
__device__ __forceinline__ void sw_gbar(unsigned* bar, int idx) {
  __syncthreads();
  if (threadIdx.x == 0) {
    unsigned* cnt = bar + idx * 2;
    unsigned* gen = bar + idx * 2 + 1;
    __threadfence();                         // release my writes
    unsigned old = __hip_atomic_fetch_add(cnt, 1u, __ATOMIC_ACQ_REL,
                                          __HIP_MEMORY_SCOPE_AGENT);
    if (old == GRID - 1) {
      __hip_atomic_store(gen, 1u, __ATOMIC_RELEASE, __HIP_MEMORY_SCOPE_AGENT);
    } else {
      while (!__hip_atomic_load(gen, __ATOMIC_ACQUIRE, __HIP_MEMORY_SCOPE_AGENT))
        __builtin_amdgcn_s_sleep(8);
    }
    __threadfence();                         // acquire remote writes
  }
  __syncthreads();
}

// ================= single kernel: prep -> qkv -> attn -> out =====================
// mode 0: cooperative launch (cg grid sync). mode 1: normal launch, sw barrier.
__global__ __launch_bounds__(256, 4) void mega_kernel(
    int mode, unsigned* __restrict__ bar,
    const float* __restrict__ x, const float* __restrict__ g,
    const float* __restrict__ Wq, const float* __restrict__ Wk,
    const float* __restrict__ Wv, const float* __restrict__ Wo,
    const float* __restrict__ bo,
    unsigned short* __restrict__ xb, unsigned char* __restrict__ sigb,
    unsigned short* __restrict__ Wt, unsigned short* __restrict__ Qb,
    unsigned short* __restrict__ Kf, unsigned short* __restrict__ Vf,
    unsigned short* __restrict__ Opart, float* __restrict__ Lpart,
    float* __restrict__ out) {
  __shared__ __align__(16) unsigned short smem[4 * 32 * PSTR];   // 17408 B, reused
  const int b = blockIdx.x, t = threadIdx.x;
  const int w = t >> 6, lane = t & 63, quad = lane >> 4, ln = lane & 15;

  // ---------------- phase 0: prep (x->bf16 | sig | weights->bf16^T) --------------
  for (int u = b; u < 1280; u += GRID) {     // x -> bf16
    int i = (u * 256 + t) * 4;
    float4 v = *(const float4*)(x + i);
    ushort4 uu;
    uu.x = f2b(v.x); uu.y = f2b(v.y); uu.z = f2b(v.z); uu.w = f2b(v.w);
    *(ushort4*)(xb + i) = uu;
  }
  if (b < 16) {                              // phase signatures
    int i = b * 256 + t;
    unsigned s = 0;
    if (g[i] != 0.f)          s |= 1u;
    if (g[NT + i] != 0.f)     s |= 2u;
    if (g[2 * NT + i] != 0.f) s |= 4u;
    sigb[i] = (unsigned char)s;
  } else if (b < 116) {                      // weights -> bf16 transposed
    unsigned short* lt = smem;               // 64*72 shorts = 9216 B
    int bb = b - 16;
    int kx = bb % 5, cy = bb / 5;
    int cm = cy % 5;
    const float* src;
    int rowbase;
    if (cy < 5)       { src = Wq; rowbase = cm * 64; }
    else if (cy < 10) { src = Wk; rowbase = 320 + cm * 64; }
    else if (cy < 15) { src = Wv; rowbase = 640 + cm * 64; }
    else              { src = Wo; rowbase = 960 + cm * 64; }
    const int c0 = cm * 64;
    const int k0 = kx * 64;
#pragma unroll
    for (int i = 0; i < 4; ++i) {
      int kr = (t >> 4) + i * 16, cc = (t & 15) * 4;
      float4 w4 = *(const float4*)&src[(size_t)(k0 + kr) * DM + c0 + cc];
      lt[(cc + 0) * 72 + kr] = f2b(w4.x);
      lt[(cc + 1) * 72 + kr] = f2b(w4.y);
      lt[(cc + 2) * 72 + kr] = f2b(w4.z);
      lt[(cc + 3) * 72 + kr] = f2b(w4.w);
    }
    __syncthreads();
#pragma unroll
    for (int i = 0; i < 2; ++i) {
      int idx = t + i * 256, cl = idx >> 3, ch = idx & 7;
      *(uint4*)&Wt[(size_t)(rowbase + cl) * DM + k0 + ch * 8] =
          *(const uint4*)&lt[cl * 72 + ch * 8];
    }
  }
  if (mode == 0) { __threadfence(); cg::this_grid().sync(); }
  else           { sw_gbar(bar, 0); }

  // ---------------- phase 1: fused QKV projection (LDS-free) ----------------
  for (int u = b; u < 960; u += GRID) {
    const int m0 = (u & 63) * 64;
    const int cy = u >> 6;                    // 0..14
    const int a = cy / 5;                     // 0=Q 1=K 2=V
    const int cc0 = (cy % 5) * 64;
    const unsigned short* Arow = xb + (size_t)(m0 + w * 16 + ln) * DM + quad * 8;
    const unsigned short* Brow = Wt + (size_t)(a * 320 + cc0 + ln) * DM + quad * 8;

    f32x4 acc[4] = {{0,0,0,0},{0,0,0,0},{0,0,0,0},{0,0,0,0}};
    for (int kc = 0; kc < 10; ++kc) {
      bf16x8 af = ld_bf8(Arow + kc * 32);
#pragma unroll
      for (int nt = 0; nt < 4; ++nt) {
        bf16x8 bf = ld_bf8(Brow + (size_t)nt * 16 * DM + kc * 32);
        acc[nt] = mfma16(af, bf, acc[nt]);
      }
    }
#pragma unroll
    for (int nt = 0; nt < 4; ++nt) {
#pragma unroll
      for (int r = 0; r < 4; ++r) {
        int row = m0 + w * 16 + quad * 4 + r;   // D row = quad*4+reg
        int cc = cc0 + nt * 16 + ln;            // D col = lane&15
        int h = cc / DH, d = cc % DH;
        if (a == 0) {
          Qb[((size_t)(h * NT + row)) * DHP + d] = f2b(acc[nt][r] * QSCALE);
        } else if (a == 1) {
          size_t base = ((size_t)h * 256 + (row >> 4)) * KFJB;
          size_t idx = (d < 32)
              ? base + (size_t)(d >> 3) * 128 + (size_t)(row & 15) * 8 + (d & 7)
              : base + 512 + (size_t)(row & 15) * 8 + (d - 32);
          Kf[idx] = f2b(acc[nt][r]);
        } else {
          size_t idx = (((((size_t)(h * 64 + (row >> 6)) * 3 + (d >> 4)) * 2 +
                          ((row >> 5) & 1)) * 4 + ((row >> 3) & 3)) * 16 +
                        (d & 15)) * 8 + (row & 7);
          Vf[idx] = f2b(acc[nt][r]);
        }
      }
    }
  }
  if (mode == 0) { __threadfence(); cg::this_grid().sync(); }
  else           { sw_gbar(bar, 1); }

  // ---------------- phase 2: barrier-free masked attention (KS=2) ----------------
  {
    const int qt = b & 31, h = (b >> 5) & 7, sp = b >> 8;   // b < 512
    const int qrow = qt * 128 + w * 32;
    const int j0 = sp * 32;

    const unsigned short* Kfh = Kf + (size_t)h * 256 * KFJB;
    const unsigned short* Vfh = Vf + (size_t)h * 196608;   // 64jt * 3ot * 2c * 512
    unsigned short* ptw = smem + w * (32 * PSTR);
    const uint4 z4 = {0, 0, 0, 0};
    const uint4 ones4 = {0x3F803F80u, 0x3F803F80u, 0x3F803F80u, 0x3F803F80u};
    const bool vone = (ln == 8);             // d=40 rows of the ot=2 V-frag -> 1.0

    bf16x8 qa[2][2];
    unsigned sqx4[2], uqx4[2];
    f32x4 o[3][2] = {{{0,0,0,0},{0,0,0,0}},{{0,0,0,0},{0,0,0,0}},{{0,0,0,0},{0,0,0,0}}};

#pragma unroll
    for (int tq = 0; tq < 2; ++tq) {
      int row = qrow + tq * 16 + ln;
      const unsigned short* Qp = Qb + ((size_t)h * NT + row) * DHP;
      qa[tq][0] = ld_bf8(Qp + quad * 8);                 // k 0..31
      uint4 q1 = z4;                                     // k 32..63: quad0 real
      if (quad == 0) q1 = *(const uint4*)(Qp + 32);
      qa[tq][1] = __builtin_bit_cast(bf16x8, q1);
      unsigned s = sigb[row];
      sqx4[tq] = s * 0x01010101u;
      uqx4[tq] = (s == 0u) ? 0xFFFFFFFFu : 0u;
      if (s == 0u) {                 // uniform row: logits exactly 0 -> p = 1
        qa[tq][0] = __builtin_bit_cast(bf16x8, z4);
        qa[tq][1] = __builtin_bit_cast(bf16x8, z4);
      }
    }

    for (int jt = j0; jt < j0 + 32; ++jt) {
      uint4 kfr0[4], kfr1[4];
#pragma unroll
      for (int nt = 0; nt < 4; ++nt) {
        const unsigned short* kb = Kfh + (size_t)(jt * 4 + nt) * KFJB;
        kfr0[nt] = *(const uint4*)(kb + lane * 8);
        kfr1[nt] = z4;
        if (lane < 16) kfr1[nt] = *(const uint4*)(kb + 512 + lane * 8);
      }

#pragma unroll
      for (int nt = 0; nt < 4; ++nt) {
        bf16x8 ka0 = __builtin_bit_cast(bf16x8, kfr0[nt]);
        bf16x8 ka1 = __builtin_bit_cast(bf16x8, kfr1[nt]);
        unsigned spj = *(const unsigned*)(sigb + jt * 64 + nt * 16 + quad * 4);
#pragma unroll
        for (int tq = 0; tq < 2; ++tq) {
          f32x4 acc = {0.f, 0.f, 0.f, 0.f};
          acc = mfma16(ka0, qa[tq][0], acc);    // S^T[j=nt*16+quad*4+r][m=ln]
          acc = mfma16(ka1, qa[tq][1], acc);
          unsigned m4 = (spj & sqx4[tq]) | uqx4[tq];   // byte r != 0 <=> unmasked
          unsigned u[4];
#pragma unroll
          for (int r = 0; r < 4; ++r) {
            unsigned mb = (m4 >> (8 * r)) & 255u;      // v_bfe
            float am = mb ? acc[r] : -3.0e38f;         // masked -> exp2 = 0
            u[r] = __builtin_bit_cast(unsigned, fexp2(am));
          }
          uint2 pk;                                    // truncate-to-bf16 pack
          pk.x = (u[0] >> 16) | (u[1] & 0xffff0000u);  // (j+0, j+1)
          pk.y = (u[2] >> 16) | (u[3] & 0xffff0000u);  // (j+2, j+3)
          *(uint2*)&ptw[(tq * 16 + ln) * PSTR + nt * 16 + quad * 4] = pk;  // b64
        }
      }
      // V fragments (6 coalesced 1KB wave loads); ones-column d=40 in-register
      uint4 vfr[6];
#pragma unroll
      for (int ot = 0; ot < 3; ++ot)
#pragma unroll
        for (int c = 0; c < 2; ++c)
          vfr[ot * 2 + c] =
              *(const uint4*)(Vfh + ((size_t)((jt * 3 + ot) * 2 + c)) * 512 + lane * 8);
      if (vone) { vfr[4] = ones4; vfr[5] = ones4; }

      asm volatile("s_waitcnt lgkmcnt(0)" ::: "memory");   // wave-private P RAW
      bf16x8 pb[2][2];
#pragma unroll
      for (int tq = 0; tq < 2; ++tq) {
        pb[tq][0] = ld_bf8(&ptw[(tq * 16 + ln) * PSTR + quad * 8]);
        pb[tq][1] = ld_bf8(&ptw[(tq * 16 + ln) * PSTR + 32 + quad * 8]);
      }
#pragma unroll
      for (int ot = 0; ot < 3; ++ot) {
        bf16x8 va0 = __builtin_bit_cast(bf16x8, vfr[ot * 2]);
        bf16x8 va1 = __builtin_bit_cast(bf16x8, vfr[ot * 2 + 1]);
#pragma unroll
        for (int tq = 0; tq < 2; ++tq) {
          o[ot][tq] = mfma16(va0, pb[tq][0], o[ot][tq]);   // O^T[d][m]
          o[ot][tq] = mfma16(va1, pb[tq][1], o[ot][tq]);
        }
      }
    }

    // epilogue: O^T d = ot*16+quad*4+r, m = ln; d=40 (ot=2,quad=2,r=0) = row-sum
#pragma unroll
    for (int tq = 0; tq < 2; ++tq) {
      int row = qrow + tq * 16 + ln;
      unsigned short* Op = Opart + (size_t)(sp * NT + row) * DM + h * DH;
#pragma unroll
      for (int ot = 0; ot < 3; ++ot) {
        int d0 = ot * 16 + quad * 4;
        if (d0 < DH) {
          uint2 pk;
          pk.x = (unsigned)f2b(o[ot][tq][0]) | ((unsigned)f2b(o[ot][tq][1]) << 16);
          pk.y = (unsigned)f2b(o[ot][tq][2]) | ((unsigned)f2b(o[ot][tq][3]) << 16);
          *(uint2*)(Op + d0) = pk;
        }
      }
      if (quad == 2)
        Lpart[sp * NT + row] = o[2][tq][0];   // MFMA-computed denominator
    }
  }
  if (mode == 0) { __threadfence(); cg::this_grid().sync(); }
  else           { sw_gbar(bar, 2); }

  // ---------------- phase 3: out projection + split-K combine + bias -------------
  for (int u = b; u < 320; u += GRID) {
    const int m0 = (u & 63) * 64;
    const int cc0 = (u >> 6) * 64;
    const int arow = m0 + w * 16 + ln;
    float ls = 0.f;
#pragma unroll
    for (int sp = 0; sp < KS; ++sp) ls += Lpart[sp * NT + arow];
    const float inv = 1.f / ls;
    const unsigned short* Brow = Wt + (size_t)(960 + cc0 + ln) * DM + quad * 8;

    f32x4 acc[4] = {{0,0,0,0},{0,0,0,0},{0,0,0,0},{0,0,0,0}};
    for (int kc = 0; kc < 10; ++kc) {
      int c8 = kc * 32 + quad * 8;
      float s8[8] = {0, 0, 0, 0, 0, 0, 0, 0};
#pragma unroll
      for (int sp = 0; sp < KS; ++sp) {
        uint4 v = *(const uint4*)(Opart + (size_t)(sp * NT + arow) * DM + c8);
        unsigned vv[4] = {v.x, v.y, v.z, v.w};
#pragma unroll
        for (int j = 0; j < 4; ++j) {
          s8[2 * j]     += __builtin_bit_cast(float, vv[j] << 16);
          s8[2 * j + 1] += __builtin_bit_cast(float, vv[j] & 0xffff0000u);
        }
      }
      unsigned short af8[8];
#pragma unroll
      for (int j = 0; j < 8; ++j) af8[j] = f2b(s8[j] * inv);
      bf16x8 af = ld_bf8(af8);
#pragma unroll
      for (int nt = 0; nt < 4; ++nt) {
        bf16x8 bf = ld_bf8(Brow + (size_t)nt * 16 * DM + kc * 32);
        acc[nt] = mfma16(af, bf, acc[nt]);
      }
    }
#pragma unroll
    for (int nt = 0; nt < 4; ++nt)
#pragma unroll
      for (int r = 0; r < 4; ++r) {
        int row = m0 + w * 16 + quad * 4 + r;
        int col = cc0 + nt * 16 + ln;
        out[(size_t)row * DM + col] = acc[nt][r] + bo[col];
      }
  }
}

// ---------------- launcher ----------------
extern "C" void kernel_launch(void* const* d_in, const int* in_sizes, int n_in,
                              void* d_out, int out_size, void* d_ws, size_t ws_size,
                              hipStream_t stream) {
  const float* x  = (const float*)d_in[0];
  const float* g  = (const float*)d_in[1];
  const float* Wq = (const float*)d_in[2];
  const float* Wk = (const float*)d_in[3];
  const float* Wv = (const float*)d_in[4];
  const float* Wo = (const float*)d_in[5];
  const float* bo = (const float*)d_in[6];
  float* out = (float*)d_out;

  char* ws = (char*)d_ws;
  const size_t SIG_OFF = 0;
  const size_t BAR_OFF = 8192;                                      // 3x(cnt,gen)
  const size_t XB_OFF  = 16384;
  const size_t WT_OFF  = XB_OFF + (size_t)NT * DM * 2;              // +2.62 MB
  const size_t QB_OFF  = WT_OFF + (size_t)1280 * DM * 2;            // +0.82 MB
  const size_t KF_OFF  = QB_OFF + (size_t)NH * NT * DHP * 2;        // +4.19 MB
  const size_t VF_OFF  = KF_OFF + (size_t)NH * 256 * KFJB * 2;      // +2.62 MB
  const size_t OP_OFF  = VF_OFF + (size_t)NH * 196608 * 2;          // +3.15 MB
  const size_t LP_OFF  = OP_OFF + (size_t)KS * NT * DM * 2;         // +5.24 MB
  unsigned char* sigb  = (unsigned char*)(ws + SIG_OFF);
  unsigned* bar        = (unsigned*)(ws + BAR_OFF);
  unsigned short* xb   = (unsigned short*)(ws + XB_OFF);
  unsigned short* Wt   = (unsigned short*)(ws + WT_OFF);
  unsigned short* Qb   = (unsigned short*)(ws + QB_OFF);
  unsigned short* Kf   = (unsigned short*)(ws + KF_OFF);
  unsigned short* Vf   = (unsigned short*)(ws + VF_OFF);
  unsigned short* Opart= (unsigned short*)(ws + OP_OFF);
  float* Lpart         = (float*)(ws + LP_OFF);

  hipMemsetAsync(ws + BAR_OFF, 0, 32, stream);   // zero sw-barrier state

  int mode = 0;
  void* args[] = {(void*)&mode, (void*)&bar,
                  (void*)&x,  (void*)&g,  (void*)&Wq, (void*)&Wk, (void*)&Wv,
                  (void*)&Wo, (void*)&bo, (void*)&xb, (void*)&sigb, (void*)&Wt,
                  (void*)&Qb, (void*)&Kf, (void*)&Vf, (void*)&Opart,
                  (void*)&Lpart, (void*)&out};
  hipError_t err = hipLaunchCooperativeKernel((const void*)mega_kernel,
                                              dim3(GRID), dim3(256), args, 0,
                                              stream);
  if (err != hipSuccess) {
    (void)hipGetLastError();                 // clear the failed-launch error
    // fallback: normal launch + software grid barrier (2 blocks/CU co-resident
    // by construction: LDS 17.4KB -> 9/CU, launch_bounds(256,4) -> VGPR<=128)
    mega_kernel<<<GRID, 256, 0, stream>>>(
        1, bar, x, g, Wq, Wk, Wv, Wo, bo, xb, sigb, Wt, Qb, Kf, Vf,
        Opart, Lpart, out);
  }
}

// Round 12
// 144.104 us; speedup vs baseline: 3.6716x; 3.6716x over previous
//
#include <hip/hip_runtime.h>
#include <hip/hip_bf16.h>
#include <stdint.h>

// Problem constants
#define NT 4096      // tokens
#define DM 320       // model dim
#define NH 8         // heads
#define DH 40        // head dim
#define KS 4         // split-K factor over the key dimension
#define QSCALE 0.22811013f  // (1/sqrt(40)) * log2(e): folded into Q so p = exp2(qk)
#define PSTR 68      // P-tile LDS row stride (ushorts): b64 8B-aligned, <=2-way banks
#define KFJB 640     // Kf shorts per 16-key block: 512 (k<32) + 128 (k=32..39, quad0)

typedef float f32x4 __attribute__((ext_vector_type(4)));
typedef __bf16 bf16x8 __attribute__((ext_vector_type(8)));

__device__ __forceinline__ unsigned short f2b(float f) {
  unsigned u = __builtin_bit_cast(unsigned, f);
  u += 0x7FFFu + ((u >> 16) & 1u);   // RNE
  return (unsigned short)(u >> 16);
}

__device__ __forceinline__ bf16x8 ld_bf8(const unsigned short* p) {
  uint4 v = *(const uint4*)p;        // 16B load
  return __builtin_bit_cast(bf16x8, v);
}

__device__ __forceinline__ f32x4 mfma16(bf16x8 a, bf16x8 b, f32x4 c) {
  return __builtin_amdgcn_mfma_f32_16x16x32_bf16(a, b, c, 0, 0, 0);
}

__device__ __forceinline__ float fexp2(float x) {
#if __has_builtin(__builtin_amdgcn_exp2f)
  return __builtin_amdgcn_exp2f(x);
#else
  float r; asm("v_exp_f32 %0, %1" : "=v"(r) : "v"(x)); return r;
#endif
}

__device__ __forceinline__ uint2 pack4(float a, float b, float c, float d) {
  uint2 pk;
  pk.x = (unsigned)f2b(a) | ((unsigned)f2b(b) << 16);
  pk.y = (unsigned)f2b(c) | ((unsigned)f2b(d) << 16);
  return pk;
}

// Fragment-major index: element (outer o in 16-tile `tile`, inner k of nk 32-tiles)
// block(tile,kc) = 512 shorts laid out [quad=(k>>3)&3][o&15][e=k&7]; wave loads 1KB.
__device__ __forceinline__ size_t fmi(int tile, int nk, int k, int o) {
  return ((size_t)tile * nk + (k >> 5)) * 512 + (size_t)((k >> 3) & 3) * 128 +
         (size_t)(o & 15) * 8 + (k & 7);
}

// ---------------- kernel 1: prep (x->xbf | sig | weights->Wtf) ----------------
// blocks 0..1279: x -> bf16 frag-major; 1280..1295: signatures;
// 1296..1395: weights -> bf16 transposed frag-major (global c: Q 0..319, K 320..,
// V 640.., O 960..1279).
__global__ __launch_bounds__(256) void prep_kernel(
    const float* __restrict__ x, const float* __restrict__ g,
    const float* __restrict__ Wq, const float* __restrict__ Wk,
    const float* __restrict__ Wv, const float* __restrict__ Wo,
    unsigned short* __restrict__ xbf, unsigned char* __restrict__ sigb,
    unsigned short* __restrict__ Wtf) {
  __shared__ __align__(16) unsigned short lt[64 * 72];
  const int b = blockIdx.x, t = threadIdx.x;
  if (b < 1280) {                       // ---- x -> bf16 frag-major
    int i = (b * 256 + t) * 4;
    int m = i / DM, k = i % DM;
    float4 v = *(const float4*)(x + i);
    ushort4 u;
    u.x = f2b(v.x); u.y = f2b(v.y); u.z = f2b(v.z); u.w = f2b(v.w);
    *(ushort4*)(xbf + fmi(m >> 4, 10, k, m)) = u;
    return;
  }
  if (b < 1296) {                       // ---- phase signatures
    int i = (b - 1280) * 256 + t;
    unsigned s = 0;
    if (g[i] != 0.f)          s |= 1u;
    if (g[NT + i] != 0.f)     s |= 2u;
    if (g[2 * NT + i] != 0.f) s |= 4u;
    sigb[i] = (unsigned char)s;
    return;
  }
  // ---- weights -> bf16 transposed frag-major
  int bb = b - 1296;
  int kx = bb % 5, cy = bb / 5;         // kx: k-tile, cy: c-tile over 4 mats
  int cm = cy % 5;
  const float* src;
  int rowbase;
  if (cy < 5)       { src = Wq; rowbase = cm * 64; }
  else if (cy < 10) { src = Wk; rowbase = 320 + cm * 64; }
  else if (cy < 15) { src = Wv; rowbase = 640 + cm * 64; }
  else              { src = Wo; rowbase = 960 + cm * 64; }
  const int c0 = cm * 64;
  const int k0 = kx * 64;
#pragma unroll
  for (int i = 0; i < 4; ++i) {         // read 64k x 64c fp32, transpose to LDS
    int kr = (t >> 4) + i * 16, cc = (t & 15) * 4;
    float4 w4 = *(const float4*)&src[(size_t)(k0 + kr) * DM + c0 + cc];
    lt[(cc + 0) * 72 + kr] = f2b(w4.x);
    lt[(cc + 1) * 72 + kr] = f2b(w4.y);
    lt[(cc + 2) * 72 + kr] = f2b(w4.z);
    lt[(cc + 3) * 72 + kr] = f2b(w4.w);
  }
  __syncthreads();
#pragma unroll
  for (int i = 0; i < 2; ++i) {         // scatter to frag-major (8-short chunks)
    int idx = t + i * 256, cl = idx >> 3, ch = idx & 7;
    int c = rowbase + cl, k = k0 + ch * 8;
    *(uint4*)&Wtf[fmi(c >> 4, 10, k, c)] = *(const uint4*)&lt[cl * 72 + ch * 8];
  }
}

// ---------------- kernel 2: fused QKV projection (all-frag-major) ----------------
// Q/K: D[c][m] via mfma(W,x) -> 4 consecutive d per thread -> uint2 stores.
// V:   D[m][c] via mfma(x,W) -> 4 consecutive m per thread -> uint2 stores.
__global__ __launch_bounds__(256, 4) void qkv_gemm(
    const unsigned short* __restrict__ xbf, const unsigned short* __restrict__ Wtf,
    unsigned short* __restrict__ Qf, unsigned short* __restrict__ Kf,
    unsigned short* __restrict__ Vf) {
  const int t = threadIdx.x;
  const int w = t >> 6, lane = t & 63, quad = lane >> 4, ln = lane & 15;
  const int m0 = blockIdx.x * 64;
  const int cy = blockIdx.y;                  // 0..14
  const int a = cy / 5;                       // 0=Q 1=K 2=V
  const int cc0 = (cy % 5) * 64;
  const int mt = (m0 >> 4) + w;
  const int ct0 = a * 20 + (cc0 >> 4);

  f32x4 acc[4] = {{0,0,0,0},{0,0,0,0},{0,0,0,0},{0,0,0,0}};
  for (int kc = 0; kc < 10; ++kc) {
    bf16x8 xf = ld_bf8(xbf + ((size_t)(mt * 10 + kc)) * 512 + lane * 8);
#pragma unroll
    for (int nt = 0; nt < 4; ++nt) {
      bf16x8 wf = ld_bf8(Wtf + ((size_t)((ct0 + nt) * 10 + kc)) * 512 + lane * 8);
      if (a < 2) acc[nt] = mfma16(wf, xf, acc[nt]);   // D[c=quad*4+r][m=ln]
      else       acc[nt] = mfma16(xf, wf, acc[nt]);   // D[m=quad*4+r][c=ln]
    }
  }
  if (a == 0) {
    const int m = m0 + w * 16 + ln;
#pragma unroll
    for (int nt = 0; nt < 4; ++nt) {
      int c = cc0 + nt * 16 + quad * 4;       // r=0 base; no h/8-boundary crossing
      int h = c / DH, d = c % DH;
      uint2 pk = pack4(acc[nt][0] * QSCALE, acc[nt][1] * QSCALE,
                       acc[nt][2] * QSCALE, acc[nt][3] * QSCALE);
      *(uint2*)&Qf[fmi(h * 256 + (m >> 4), 2, d, m)] = pk;
    }
  } else if (a == 1) {
    const int m = m0 + w * 16 + ln;
#pragma unroll
    for (int nt = 0; nt < 4; ++nt) {
      int c = cc0 + nt * 16 + quad * 4;
      int h = c / DH, d = c % DH;
      uint2 pk = pack4(acc[nt][0], acc[nt][1], acc[nt][2], acc[nt][3]);
      size_t base = ((size_t)h * 256 + (m >> 4)) * KFJB;
      size_t idx = (d < 32)
          ? base + (size_t)(d >> 3) * 128 + (size_t)(m & 15) * 8 + (d & 7)
          : base + 512 + (size_t)(m & 15) * 8 + (d - 32);
      *(uint2*)&Kf[idx] = pk;
    }
  } else {
    const int mb = m0 + w * 16 + quad * 4;    // r=0 base (4 consecutive m)
#pragma unroll
    for (int nt = 0; nt < 4; ++nt) {
      int c = cc0 + nt * 16 + ln;
      int h = c / DH, d = c % DH;
      uint2 pk = pack4(acc[nt][0], acc[nt][1], acc[nt][2], acc[nt][3]);
      size_t idx = ((((((size_t)(h * 64 + (mb >> 6)) * 3 + (d >> 4)) * 2 +
                       ((mb >> 5) & 1)) * 4 + ((mb >> 3) & 3)) * 16 + (d & 15))) * 8 +
                   (mb & 7);
      *(uint2*)&Vf[idx] = pk;
    }
  }
}

// ---------------- kernel 3: barrier-free masked attention ----------------
// grid (32 q-tiles of 128 rows, 8 heads, KS=4); block 256 = 4 waves x 32 q-rows.
__global__ __launch_bounds__(256, 4) void attn_kernel(
    const unsigned short* __restrict__ Qf, const unsigned short* __restrict__ Kf,
    const unsigned short* __restrict__ Vf, const unsigned char* __restrict__ sigb,
    unsigned short* __restrict__ Opf, float* __restrict__ Lpart) {
  __shared__ __align__(16) unsigned short pt[4][32 * PSTR];   // per-wave P^T 17408 B
  const int t = threadIdx.x;
  const int w = t >> 6, lane = t & 63, quad = lane >> 4, ln = lane & 15;
  const int h = blockIdx.y, qt = blockIdx.x, sp = blockIdx.z;
  const int qrow = qt * 128 + w * 32;
  const int j0 = sp * 16;

  const unsigned short* Kfh = Kf + (size_t)h * 256 * KFJB;
  const unsigned short* Vfh = Vf + (size_t)h * 196608;   // 64jt * 3ot * 2c * 512
  unsigned short* ptw = pt[w];
  const uint4 z4 = {0, 0, 0, 0};
  const uint4 ones4 = {0x3F803F80u, 0x3F803F80u, 0x3F803F80u, 0x3F803F80u};
  const bool vone = (ln == 8);             // d=40 rows of the ot=2 V-frag -> 1.0

  bf16x8 qa[2][2];
  unsigned sqx4[2], uqx4[2];
  f32x4 o[3][2] = {{{0,0,0,0},{0,0,0,0}},{{0,0,0,0},{0,0,0,0}},{{0,0,0,0},{0,0,0,0}}};

#pragma unroll
  for (int tq = 0; tq < 2; ++tq) {
    int row = qrow + tq * 16 + ln;
    size_t qbase = ((size_t)(h * 256 + qt * 8 + w * 2 + tq) * 2) * 512;
    qa[tq][0] = ld_bf8(Qf + qbase + lane * 8);          // k 0..31, contiguous 1KB
    uint4 q1 = z4;                                      // k 32..63: quad0 real
    if (quad == 0) q1 = *(const uint4*)(Qf + qbase + 512 + lane * 8);
    qa[tq][1] = __builtin_bit_cast(bf16x8, q1);
    unsigned s = sigb[row];
    sqx4[tq] = s * 0x01010101u;
    uqx4[tq] = (s == 0u) ? 0xFFFFFFFFu : 0u;
    if (s == 0u) {                 // uniform row: logits exactly 0 -> p = 1
      qa[tq][0] = __builtin_bit_cast(bf16x8, z4);
      qa[tq][1] = __builtin_bit_cast(bf16x8, z4);
    }
  }

  for (int jt = j0; jt < j0 + 16; ++jt) {
    // K fragments from compact Kf: 4 x 1KB + 4 x 256B (quad0) coalesced loads
    uint4 kfr0[4], kfr1[4];
#pragma unroll
    for (int nt = 0; nt < 4; ++nt) {
      const unsigned short* kb = Kfh + (size_t)(jt * 4 + nt) * KFJB;
      kfr0[nt] = *(const uint4*)(kb + lane * 8);
      kfr1[nt] = z4;
      if (lane < 16) kfr1[nt] = *(const uint4*)(kb + 512 + lane * 8);
    }

#pragma unroll
    for (int nt = 0; nt < 4; ++nt) {
      bf16x8 ka0 = __builtin_bit_cast(bf16x8, kfr0[nt]);
      bf16x8 ka1 = __builtin_bit_cast(bf16x8, kfr1[nt]);
      unsigned spj = *(const unsigned*)(sigb + jt * 64 + nt * 16 + quad * 4);
#pragma unroll
      for (int tq = 0; tq < 2; ++tq) {
        f32x4 acc = {0.f, 0.f, 0.f, 0.f};
        acc = mfma16(ka0, qa[tq][0], acc);    // S^T[j=nt*16+quad*4+r][m=ln]
        acc = mfma16(ka1, qa[tq][1], acc);
        unsigned m4 = (spj & sqx4[tq]) | uqx4[tq];   // byte r != 0 <=> unmasked
        unsigned u[4];
#pragma unroll
        for (int r = 0; r < 4; ++r) {
          unsigned mb = (m4 >> (8 * r)) & 255u;      // v_bfe
          float am = mb ? acc[r] : -3.0e38f;         // masked -> exp2 = 0
          u[r] = __builtin_bit_cast(unsigned, fexp2(am));
        }
        uint2 pk;                                    // truncate-to-bf16 pack
        pk.x = (u[0] >> 16) | (u[1] & 0xffff0000u);  // (j+0, j+1)
        pk.y = (u[2] >> 16) | (u[3] & 0xffff0000u);  // (j+2, j+3)
        *(uint2*)&ptw[(tq * 16 + ln) * PSTR + nt * 16 + quad * 4] = pk;  // b64
      }
    }
    // V fragments (6 coalesced 1KB wave loads); ones-column d=40 in-register
    uint4 vfr[6];
#pragma unroll
    for (int ot = 0; ot < 3; ++ot)
#pragma unroll
      for (int c = 0; c < 2; ++c)
        vfr[ot * 2 + c] =
            *(const uint4*)(Vfh + ((size_t)((jt * 3 + ot) * 2 + c)) * 512 + lane * 8);
    if (vone) { vfr[4] = ones4; vfr[5] = ones4; }

    asm volatile("s_waitcnt lgkmcnt(0)" ::: "memory");   // wave-private P RAW
    bf16x8 pb[2][2];
#pragma unroll
    for (int tq = 0; tq < 2; ++tq) {
      pb[tq][0] = ld_bf8(&ptw[(tq * 16 + ln) * PSTR + quad * 8]);
      pb[tq][1] = ld_bf8(&ptw[(tq * 16 + ln) * PSTR + 32 + quad * 8]);
    }
#pragma unroll
    for (int ot = 0; ot < 3; ++ot) {
      bf16x8 va0 = __builtin_bit_cast(bf16x8, vfr[ot * 2]);
      bf16x8 va1 = __builtin_bit_cast(bf16x8, vfr[ot * 2 + 1]);
#pragma unroll
      for (int tq = 0; tq < 2; ++tq) {
        o[ot][tq] = mfma16(va0, pb[tq][0], o[ot][tq]);   // O^T[d][m]
        o[ot][tq] = mfma16(va1, pb[tq][1], o[ot][tq]);
      }
    }
  }

  // epilogue: O^T d = ot*16+quad*4+r; write frag-major Opf; d=40 -> denominator
#pragma unroll
  for (int tq = 0; tq < 2; ++tq) {
    int m = qrow + tq * 16 + ln;
#pragma unroll
    for (int ot = 0; ot < 3; ++ot) {
      int d0 = ot * 16 + quad * 4;
      if (d0 < DH) {
        int c = h * DH + d0;                  // 4 consecutive c, no 8-crossing
        uint2 pk = pack4(o[ot][tq][0], o[ot][tq][1], o[ot][tq][2], o[ot][tq][3]);
        *(uint2*)&Opf[fmi(sp * 256 + (m >> 4), 10, c, m)] = pk;
      }
    }
    if (quad == 2)
      Lpart[sp * NT + m] = o[2][tq][0];       // MFMA-computed denominator
  }
}

// ---------------- kernel 4: out projection + split-K combine + bias ----------------
// D[c][m] via mfma(Wo, A): float4 out stores + float4 bias loads.
__global__ __launch_bounds__(256, 4) void out_gemm(
    const unsigned short* __restrict__ Opf, const float* __restrict__ Lpart,
    const unsigned short* __restrict__ Wtf, const float* __restrict__ bo,
    float* __restrict__ out) {
  const int t = threadIdx.x;
  const int w = t >> 6, lane = t & 63, quad = lane >> 4, ln = lane & 15;
  const int m0 = blockIdx.x * 64;
  const int cc0 = blockIdx.y * 64;
  const int mt = (m0 >> 4) + w;
  const int m = m0 + w * 16 + ln;
  const int ct0 = 60 + (cc0 >> 4);
  float ls = 0.f;
#pragma unroll
  for (int sp = 0; sp < KS; ++sp) ls += Lpart[sp * NT + m];
  const float inv = 1.f / ls;

  f32x4 acc[4] = {{0,0,0,0},{0,0,0,0},{0,0,0,0},{0,0,0,0}};
  for (int kc = 0; kc < 10; ++kc) {
    float s8[8] = {0, 0, 0, 0, 0, 0, 0, 0};
#pragma unroll
    for (int sp = 0; sp < KS; ++sp) {
      uint4 v = *(const uint4*)(Opf + ((size_t)((sp * 256 + mt) * 10 + kc)) * 512 +
                                lane * 8);
      unsigned vv[4] = {v.x, v.y, v.z, v.w};
#pragma unroll
      for (int j = 0; j < 4; ++j) {
        s8[2 * j]     += __builtin_bit_cast(float, vv[j] << 16);
        s8[2 * j + 1] += __builtin_bit_cast(float, vv[j] & 0xffff0000u);
      }
    }
    unsigned short af8[8];
#pragma unroll
    for (int j = 0; j < 8; ++j) af8[j] = f2b(s8[j] * inv);
    bf16x8 af = ld_bf8(af8);
#pragma unroll
    for (int nt = 0; nt < 4; ++nt) {
      bf16x8 wf = ld_bf8(Wtf + ((size_t)((ct0 + nt) * 10 + kc)) * 512 + lane * 8);
      acc[nt] = mfma16(wf, af, acc[nt]);      // D[c=quad*4+r][m=ln]
    }
  }
#pragma unroll
  for (int nt = 0; nt < 4; ++nt) {
    int c = cc0 + nt * 16 + quad * 4;
    float4 bv = *(const float4*)(bo + c);
    float4 ov;
    ov.x = acc[nt][0] + bv.x;
    ov.y = acc[nt][1] + bv.y;
    ov.z = acc[nt][2] + bv.z;
    ov.w = acc[nt][3] + bv.w;
    *(float4*)(out + (size_t)m * DM + c) = ov;
  }
}

// ---------------- launcher ----------------
extern "C" void kernel_launch(void* const* d_in, const int* in_sizes, int n_in,
                              void* d_out, int out_size, void* d_ws, size_t ws_size,
                              hipStream_t stream) {
  const float* x  = (const float*)d_in[0];
  const float* g  = (const float*)d_in[1];
  const float* Wq = (const float*)d_in[2];
  const float* Wk = (const float*)d_in[3];
  const float* Wv = (const float*)d_in[4];
  const float* Wo = (const float*)d_in[5];
  const float* bo = (const float*)d_in[6];
  float* out = (float*)d_out;

  char* ws = (char*)d_ws;
  const size_t SIG_OFF = 0;
  const size_t XBF_OFF = 16384;
  const size_t WTF_OFF = XBF_OFF + (size_t)NT * DM * 2;             // +2.62 MB
  const size_t QF_OFF  = WTF_OFF + (size_t)1280 * DM * 2;           // +0.82 MB
  const size_t KF_OFF  = QF_OFF + (size_t)NH * 256 * 2 * 512 * 2;   // +4.19 MB
  const size_t VF_OFF  = KF_OFF + (size_t)NH * 256 * KFJB * 2;      // +2.62 MB
  const size_t OPF_OFF = VF_OFF + (size_t)NH * 196608 * 2;          // +3.15 MB
  const size_t LP_OFF  = OPF_OFF + (size_t)KS * 256 * 10 * 512 * 2; // +10.49 MB
  unsigned char* sigb  = (unsigned char*)(ws + SIG_OFF);
  unsigned short* xbf  = (unsigned short*)(ws + XBF_OFF);
  unsigned short* Wtf  = (unsigned short*)(ws + WTF_OFF);
  unsigned short* Qf   = (unsigned short*)(ws + QF_OFF);
  unsigned short* Kf   = (unsigned short*)(ws + KF_OFF);
  unsigned short* Vf   = (unsigned short*)(ws + VF_OFF);
  unsigned short* Opf  = (unsigned short*)(ws + OPF_OFF);
  float* Lpart         = (float*)(ws + LP_OFF);

  // No memset: Qf half-1 quad>=1 garbage zeroed in-register; Vf d=40 ones
  // in-register; Vf d=41..47 garbage feeds only discarded lanes (no NaN).
  prep_kernel<<<1396, 256, 0, stream>>>(x, g, Wq, Wk, Wv, Wo, xbf, sigb, Wtf);
  qkv_gemm<<<dim3(64, 15), 256, 0, stream>>>(xbf, Wtf, Qf, Kf, Vf);
  attn_kernel<<<dim3(32, NH, KS), 256, 0, stream>>>(Qf, Kf, Vf, sigb, Opf, Lpart);
  out_gemm<<<dim3(64, 5), 256, 0, stream>>>(Opf, Lpart, Wtf, bo, out);
}